// Round 6
// baseline (27134.128 us; speedup 1.0000x reference)
//
#include <hip/hip_runtime.h>
#include <math.h>

#define TLEN 512
#define BSZ  64
#define EDIM 256
#define HDIM 256
#define GDIM 1024
#define KTAG 32

__device__ __forceinline__ float sigf(float x) { return 1.0f / (1.0f + expf(-x)); }

// ---------------------------------------------------------------------------
// Transpose W_hh [1024][256] -> Wt4 [64 kq][1024 gate] of float4 (4 k each).
// ---------------------------------------------------------------------------
__global__ __launch_bounds__(256)
void transpose_w(const float* __restrict__ W, float4* __restrict__ Wt)
{
    const int t = threadIdx.x;
    const int j = blockIdx.x * 4 + (t >> 6);   // gate row 0..1023
    const int l = t & 63;                      // k-quad 0..63
    float4 v = *(const float4*)(W + (size_t)j * HDIM + l * 4);
    Wt[(size_t)l * GDIM + j] = v;
}

// ---------------------------------------------------------------------------
// Dual-direction GEMM over a time-chunk of C steps (C*64 rows).
// ---------------------------------------------------------------------------
template<int KDIM, bool GATHER>
__global__ __launch_bounds__(256)
void gemm_dual(const float* __restrict__ A, const int* __restrict__ idx,
               const float* __restrict__ Bf, const float* __restrict__ Bb,
               const float* __restrict__ b1f, const float* __restrict__ b2f,
               const float* __restrict__ b1b, const float* __restrict__ b2b,
               float* __restrict__ Cf, float* __restrict__ Cb,
               int t0f, int t0b, int r0f, int r0b)
{
    __shared__ __align__(16) float As[8][132];
    __shared__ __align__(16) float Bs[8][132];
    const int mt = blockIdx.x * 128;
    const int ng = blockIdx.y * 128;
    const bool isF = (ng < GDIM);
    const int nt = isF ? ng : (ng - GDIM);
    const float* Bw = isF ? Bf : Bb;
    const float* bias1 = isF ? b1f : b1b;
    const float* bias2 = isF ? b2f : b2b;
    float* C = isF ? Cf : Cb;
    const int t0 = isF ? t0f : t0b;
    const int r0 = isF ? r0f : r0b;

    const int tid = threadIdx.x;
    const int tx = tid & 15;
    const int ty = tid >> 4;
    const int srow = tid >> 1;        // 0..127
    const int skq = (tid & 1) * 4;    // 0 or 4

    const float* arow;
    if (GATHER) {
        int m = mt + srow;            // local row in chunk
        int t = t0 + (m >> 6);
        int b = m & 63;
        arow = A + (size_t)idx[b * TLEN + t] * (size_t)KDIM; // A = emb table
    } else {
        arow = A + (size_t)(r0 + mt + srow) * (size_t)KDIM;
    }
    const float* brow = Bw + (size_t)(nt + srow) * (size_t)KDIM;

    float acc[8][8];
    #pragma unroll
    for (int i = 0; i < 8; ++i)
        #pragma unroll
        for (int j = 0; j < 8; ++j) acc[i][j] = 0.0f;

    for (int k0 = 0; k0 < KDIM; k0 += 8) {
        float4 av = *(const float4*)(arow + k0 + skq);
        float4 bv = *(const float4*)(brow + k0 + skq);
        __syncthreads();
        As[skq + 0][srow] = av.x; As[skq + 1][srow] = av.y;
        As[skq + 2][srow] = av.z; As[skq + 3][srow] = av.w;
        Bs[skq + 0][srow] = bv.x; Bs[skq + 1][srow] = bv.y;
        Bs[skq + 2][srow] = bv.z; Bs[skq + 3][srow] = bv.w;
        __syncthreads();
        #pragma unroll
        for (int k = 0; k < 8; ++k) {
            float a[8], bb2[8];
            *(float4*)(a)       = *(const float4*)&As[k][ty * 8];
            *(float4*)(a + 4)   = *(const float4*)&As[k][ty * 8 + 4];
            *(float4*)(bb2)     = *(const float4*)&Bs[k][tx * 8];
            *(float4*)(bb2 + 4) = *(const float4*)&Bs[k][tx * 8 + 4];
            #pragma unroll
            for (int i = 0; i < 8; ++i)
                #pragma unroll
                for (int j = 0; j < 8; ++j)
                    acc[i][j] = fmaf(a[i], bb2[j], acc[i][j]);
        }
    }

    float bs[8];
    #pragma unroll
    for (int j = 0; j < 8; ++j) {
        int n = nt + tx * 8 + j;
        bs[j] = bias1[n] + bias2[n];
    }
    #pragma unroll
    for (int i = 0; i < 8; ++i) {
        size_t row = (size_t)(mt + ty * 8 + i);      // local chunk row
        float* cp = C + row * GDIM + nt + tx * 8;
        float4 v0 = make_float4(acc[i][0] + bs[0], acc[i][1] + bs[1],
                                acc[i][2] + bs[2], acc[i][3] + bs[3]);
        float4 v1 = make_float4(acc[i][4] + bs[4], acc[i][5] + bs[5],
                                acc[i][6] + bs[6], acc[i][7] + bs[7]);
        *(float4*)cp = v0;
        *(float4*)(cp + 4) = v1;
    }
}

// ---------------------------------------------------------------------------
// LSTM recurrence, weight-stationary in REGISTERS.
// 128 blocks: blk = dir*64 + b (one batch-element chain per block/CU).
// Thread j owns gate j; its W row (256 f32 = 64 float4 = 256 VGPRs) is
// loaded ONCE per dispatch from the transposed Wt, then reused all C steps.
// Per step: 64 uniform (broadcast) ds_read_b128 of h + 256 FMA, no W traffic.
// ---------------------------------------------------------------------------
template<bool TOXBUF>
__global__ __launch_bounds__(1024)
void lstm_rec(const float* __restrict__ gx_f, const float* __restrict__ gx_b,
              const float4* __restrict__ Wt_f, const float4* __restrict__ Wt_b,
              float* __restrict__ xout, float* __restrict__ hbuf,
              float* __restrict__ state,
              int t0f, int t0b, int C, int init)
{
    const int blk = blockIdx.x;     // 0..127
    const int dir = blk >> 6;       // 0 = fwd, 1 = bwd
    const int b = blk & 63;
    const float* gx = dir ? gx_b : gx_f;
    const float4* Wt = dir ? Wt_b : Wt_f;
    const int j = threadIdx.x;      // gate index 0..1023

    __shared__ __align__(16) float h_lds[HDIM];
    __shared__ __align__(16) float g_lds[GDIM];

    float* st = state + (((size_t)dir * BSZ + b) * 2) * HDIM;  // [h|c][256]

    float cc = 0.0f;
    if (j < HDIM) {
        if (init) h_lds[j] = 0.0f;
        else { h_lds[j] = st[j]; cc = st[HDIM + j]; }
    }
    // W row j -> registers (coalesced: lane-contiguous per kq plane)
    float4 w[64];
    #pragma unroll
    for (int kq = 0; kq < 64; ++kq)
        w[kq] = Wt[(size_t)kq * GDIM + j];
    __syncthreads();

    for (int s = 0; s < C; ++s) {
        const int tloc = dir ? (C - 1 - s) : s;
        const int tglob = (dir ? t0b : t0f) + tloc;
        float gxv = gx[((size_t)tloc * BSZ + b) * GDIM + j];
        float a0 = 0.0f, a1 = 0.0f;            // 2 chains to pipeline FMA
        #pragma unroll
        for (int kq = 0; kq < 64; kq += 2) {
            float4 ha = *(const float4*)&h_lds[kq * 4];
            float4 hb = *(const float4*)&h_lds[kq * 4 + 4];
            a0 = fmaf(w[kq].x, ha.x, a0);
            a0 = fmaf(w[kq].y, ha.y, a0);
            a0 = fmaf(w[kq].z, ha.z, a0);
            a0 = fmaf(w[kq].w, ha.w, a0);
            a1 = fmaf(w[kq + 1].x, hb.x, a1);
            a1 = fmaf(w[kq + 1].y, hb.y, a1);
            a1 = fmaf(w[kq + 1].z, hb.z, a1);
            a1 = fmaf(w[kq + 1].w, hb.w, a1);
        }
        g_lds[j] = a0 + a1 + gxv;
        __syncthreads();   // all h reads done, all gates staged
        if (j < HDIM) {
            float iv = sigf(g_lds[j]);
            float fv = sigf(g_lds[j + 256]);
            float gv = tanhf(g_lds[j + 512]);
            float ov = sigf(g_lds[j + 768]);
            cc = fv * cc + iv * gv;
            float hv = ov * tanhf(cc);
            h_lds[j] = hv;
            if (TOXBUF) {
                xout[((size_t)tglob * BSZ + b) * 512 + (size_t)dir * HDIM + j] = hv;
            } else {
                hbuf[(((size_t)dir * C + tloc) * BSZ + b) * HDIM + j] = hv;
            }
        }
        __syncthreads();   // h_lds ready for next step
    }
    if (j < HDIM) { st[j] = h_lds[j]; st[HDIM + j] = cc; }
}

// ---------------------------------------------------------------------------
// Partial emissions from one chunk of layer-1 h (both dirs).
// ---------------------------------------------------------------------------
__global__ __launch_bounds__(256)
void emis_part(const float* __restrict__ hbuf, const float* __restrict__ Wo,
               float* __restrict__ em_f, float* __restrict__ em_b,
               int t0f, int t0b, int C)
{
    __shared__ float Ws[128][33];
    const int dir = blockIdx.y;
    const int tid = threadIdx.x;
    const int r = tid >> 5;          // 0..7
    const int kk = tid & 31;
    const int mloc = blockIdx.x * 8 + r;      // 0..C*64-1
    const float* hrow = hbuf + ((size_t)dir * C * BSZ + mloc) * HDIM;
    float* emo = dir ? em_b : em_f;
    const int t0 = dir ? t0b : t0f;
    float acc = 0.0f;
    for (int kc = 0; kc < HDIM; kc += 128) {
        __syncthreads();
        for (int i = tid; i < KTAG * 128; i += 256) {
            int wk = i >> 7;         // tag row 0..31
            int k = i & 127;
            Ws[k][wk] = Wo[(size_t)wk * 512 + dir * HDIM + kc + k];
        }
        __syncthreads();
        #pragma unroll 8
        for (int k4 = 0; k4 < 32; ++k4) {
            float4 xv = *(const float4*)(hrow + kc + k4 * 4);
            acc = fmaf(xv.x, Ws[k4 * 4 + 0][kk], acc);
            acc = fmaf(xv.y, Ws[k4 * 4 + 1][kk], acc);
            acc = fmaf(xv.z, Ws[k4 * 4 + 2][kk], acc);
            acc = fmaf(xv.w, Ws[k4 * 4 + 3][kk], acc);
        }
    }
    const int tloc = mloc >> 6;
    const int b = mloc & 63;
    emo[(((size_t)(t0 + tloc)) * BSZ + b) * KTAG + kk] = acc;
}

// ---------------------------------------------------------------------------
// Viterbi: one block (64 threads, 32 active) per batch element.
// ---------------------------------------------------------------------------
__global__ __launch_bounds__(64)
void viterbi(const float* __restrict__ em_f, const float* __restrict__ em_b,
             const float* __restrict__ bo,
             const float* __restrict__ st, const float* __restrict__ en,
             const float* __restrict__ tr,
             unsigned char* __restrict__ bp, int* __restrict__ out)
{
    const int b = blockIdx.x;
    const int lane = threadIdx.x;
    __shared__ float s_tr[KTAG][KTAG + 1];
    __shared__ float s_sc[KTAG];
    __shared__ float s_fin[KTAG];
    for (int i = lane; i < KTAG * KTAG; i += 64)
        s_tr[i >> 5][i & 31] = tr[i];
    if (lane < KTAG) {
        size_t e0 = (size_t)b * KTAG + lane;
        s_sc[lane] = st[lane] + em_f[e0] + em_b[e0] + bo[lane];
    }
    __syncthreads();
    for (int t = 1; t < TLEN; ++t) {
        float best = -3.0e38f;
        int arg = 0;
        if (lane < KTAG) {
            #pragma unroll
            for (int i = 0; i < KTAG; ++i) {
                float c = s_sc[i] + s_tr[i][lane];
                if (c > best) { best = c; arg = i; }
            }
        }
        __syncthreads();
        if (lane < KTAG) {
            size_t et = ((size_t)t * BSZ + b) * KTAG + lane;
            s_sc[lane] = best + em_f[et] + em_b[et] + bo[lane];
            bp[((size_t)(t - 1) * BSZ + b) * KTAG + lane] = (unsigned char)arg;
        }
        __syncthreads();
    }
    if (lane < KTAG) s_fin[lane] = s_sc[lane] + en[lane];
    __syncthreads();
    if (lane == 0) {
        int tag = 0;
        float bv = s_fin[0];
        for (int i = 1; i < KTAG; ++i)
            if (s_fin[i] > bv) { bv = s_fin[i]; tag = i; }
        out[(size_t)b * TLEN + (TLEN - 1)] = tag;
        for (int t = TLEN - 2; t >= 0; --t) {
            tag = bp[((size_t)t * BSZ + b) * KTAG + tag];
            out[(size_t)b * TLEN + t] = tag;
        }
    }
}

// ---------------------------------------------------------------------------
extern "C" void kernel_launch(void* const* d_in, const int* in_sizes, int n_in,
                              void* d_out, int out_size, void* d_ws, size_t ws_size,
                              hipStream_t stream)
{
    (void)in_sizes; (void)n_in; (void)out_size;
    const int*   inputs     = (const int*)d_in[0];
    const float* emb        = (const float*)d_in[1];
    const float* W_ih_l0_f  = (const float*)d_in[2];
    const float* W_hh_l0_f  = (const float*)d_in[3];
    const float* b_ih_l0_f  = (const float*)d_in[4];
    const float* b_hh_l0_f  = (const float*)d_in[5];
    const float* W_ih_l0_b  = (const float*)d_in[6];
    const float* W_hh_l0_b  = (const float*)d_in[7];
    const float* b_ih_l0_b  = (const float*)d_in[8];
    const float* b_hh_l0_b  = (const float*)d_in[9];
    const float* W_ih_l1_f  = (const float*)d_in[10];
    const float* W_hh_l1_f  = (const float*)d_in[11];
    const float* b_ih_l1_f  = (const float*)d_in[12];
    const float* b_hh_l1_f  = (const float*)d_in[13];
    const float* W_ih_l1_b  = (const float*)d_in[14];
    const float* W_hh_l1_b  = (const float*)d_in[15];
    const float* b_ih_l1_b  = (const float*)d_in[16];
    const float* b_hh_l1_b  = (const float*)d_in[17];
    const float* W_out      = (const float*)d_in[18];
    const float* b_out      = (const float*)d_in[19];
    const float* start_tr   = (const float*)d_in[20];
    const float* end_tr     = (const float*)d_in[21];
    const float* trans      = (const float*)d_in[22];

    // workspace: xbuf 64MB | gx_f C*256KB | gx_b C*256KB | hbuf C*128KB |
    //   em_f 4MB | em_b 4MB | bp 1MB | state 512KB | wt_f 1MB | wt_b 1MB
    const size_t XBUF = 67108864;
    const size_t TAIL = 4194304ull * 2 + 1048576 + 524288 + 2097152;
    int C = 16;
    for (int cand = TLEN; cand >= 16; cand >>= 1) {
        size_t need = XBUF + (size_t)cand * (524288 + 131072) + TAIL;
        if (need <= ws_size) { C = cand; break; }
    }
    char* ws = (char*)d_ws;
    float* xbuf = (float*)(ws);
    float* gx_f = (float*)(ws + XBUF);
    float* gx_b = (float*)(ws + XBUF + (size_t)C * 262144);
    float* hbuf = (float*)(ws + XBUF + (size_t)C * 524288);
    char*  tail = ws + XBUF + (size_t)C * (524288 + 131072);
    float* em_f = (float*)(tail);
    float* em_b = (float*)(tail + 4194304);
    unsigned char* bp = (unsigned char*)(tail + 2 * 4194304);
    float* state = (float*)(tail + 2 * 4194304 + 1048576);
    float4* wt_f = (float4*)(tail + 2 * 4194304 + 1048576 + 524288);
    float4* wt_b = (float4*)(tail + 2 * 4194304 + 1048576 + 524288 + 1048576);
    int* outi = (int*)d_out;

    const int nc = TLEN / C;
    dim3 gg(C / 2, 16);   // (C*64/128) m-tiles x 2048/128 n-tiles

    // ----- layer 0 -----
    transpose_w<<<256, 256, 0, stream>>>(W_hh_l0_f, wt_f);
    transpose_w<<<256, 256, 0, stream>>>(W_hh_l0_b, wt_b);
    for (int c = 0; c < nc; ++c) {
        int t0f = c * C;
        int t0b = TLEN - (c + 1) * C;
        gemm_dual<EDIM, true><<<gg, 256, 0, stream>>>(
            emb, inputs, W_ih_l0_f, W_ih_l0_b,
            b_ih_l0_f, b_hh_l0_f, b_ih_l0_b, b_hh_l0_b,
            gx_f, gx_b, t0f, t0b, 0, 0);
        lstm_rec<true><<<128, 1024, 0, stream>>>(
            gx_f, gx_b, wt_f, wt_b, xbuf, nullptr, state,
            t0f, t0b, C, c == 0 ? 1 : 0);
    }
    // ----- layer 1 ----- (xbuf READ-ONLY here; h -> hbuf -> em parts)
    transpose_w<<<256, 256, 0, stream>>>(W_hh_l1_f, wt_f);
    transpose_w<<<256, 256, 0, stream>>>(W_hh_l1_b, wt_b);
    for (int c = 0; c < nc; ++c) {
        int t0f = c * C;
        int t0b = TLEN - (c + 1) * C;
        gemm_dual<512, false><<<gg, 256, 0, stream>>>(
            xbuf, nullptr, W_ih_l1_f, W_ih_l1_b,
            b_ih_l1_f, b_hh_l1_f, b_ih_l1_b, b_hh_l1_b,
            gx_f, gx_b, t0f, t0b, t0f * BSZ, t0b * BSZ);
        lstm_rec<false><<<128, 1024, 0, stream>>>(
            gx_f, gx_b, wt_f, wt_b, nullptr, hbuf, state,
            t0f, t0b, C, c == 0 ? 1 : 0);
        dim3 ge(C * 8, 2);
        emis_part<<<ge, 256, 0, stream>>>(hbuf, W_out, em_f, em_b, t0f, t0b, C);
    }

    // viterbi decode -> int32 tags
    viterbi<<<64, 64, 0, stream>>>(em_f, em_b, b_out, start_tr, end_tr, trans,
                                   bp, outi);
}

// Round 7
// 22469.913 us; speedup vs baseline: 1.2076x; 1.2076x over previous
//
#include <hip/hip_runtime.h>
#include <math.h>

#define TLEN 512
#define BSZ  64
#define EDIM 256
#define HDIM 256
#define GDIM 1024
#define KTAG 32

__device__ __forceinline__ float sigf(float x) { return 1.0f / (1.0f + expf(-x)); }

// ---------------------------------------------------------------------------
// Transpose W_hh [1024][256] -> Wt4 [64 kq][1024 gate] of float4 (4 k each).
// ---------------------------------------------------------------------------
__global__ __launch_bounds__(256)
void transpose_w(const float* __restrict__ W, float4* __restrict__ Wt)
{
    const int t = threadIdx.x;
    const int j = blockIdx.x * 4 + (t >> 6);   // gate row 0..1023
    const int l = t & 63;                      // k-quad 0..63
    float4 v = *(const float4*)(W + (size_t)j * HDIM + l * 4);
    Wt[(size_t)l * GDIM + j] = v;
}

// ---------------------------------------------------------------------------
// Dual-direction GEMM over a time-chunk of C steps (C*64 rows).
// Thread cols remapped to two half-tiles (tx*4 and 64+tx*4) so B-fragment
// ds_read_b128 banks start at {0,4,...,60} -> 2-way (free) instead of 4-way.
// ---------------------------------------------------------------------------
template<int KDIM, bool GATHER>
__global__ __launch_bounds__(256)
void gemm_dual(const float* __restrict__ A, const int* __restrict__ idx,
               const float* __restrict__ Bf, const float* __restrict__ Bb,
               const float* __restrict__ b1f, const float* __restrict__ b2f,
               const float* __restrict__ b1b, const float* __restrict__ b2b,
               float* __restrict__ Cf, float* __restrict__ Cb,
               int t0f, int t0b, int r0f, int r0b)
{
    __shared__ __align__(16) float As[8][132];
    __shared__ __align__(16) float Bs[8][132];
    const int mt = blockIdx.x * 128;
    const int ng = blockIdx.y * 128;
    const bool isF = (ng < GDIM);
    const int nt = isF ? ng : (ng - GDIM);
    const float* Bw = isF ? Bf : Bb;
    const float* bias1 = isF ? b1f : b1b;
    const float* bias2 = isF ? b2f : b2b;
    float* C = isF ? Cf : Cb;
    const int t0 = isF ? t0f : t0b;
    const int r0 = isF ? r0f : r0b;

    const int tid = threadIdx.x;
    const int tx = tid & 15;
    const int ty = tid >> 4;
    const int srow = tid >> 1;        // 0..127
    const int skq = (tid & 1) * 4;    // 0 or 4

    const float* arow;
    if (GATHER) {
        int m = mt + srow;            // local row in chunk
        int t = t0 + (m >> 6);
        int b = m & 63;
        arow = A + (size_t)idx[b * TLEN + t] * (size_t)KDIM; // A = emb table
    } else {
        arow = A + (size_t)(r0 + mt + srow) * (size_t)KDIM;
    }
    const float* brow = Bw + (size_t)(nt + srow) * (size_t)KDIM;

    float acc[8][8];
    #pragma unroll
    for (int i = 0; i < 8; ++i)
        #pragma unroll
        for (int j = 0; j < 8; ++j) acc[i][j] = 0.0f;

    for (int k0 = 0; k0 < KDIM; k0 += 8) {
        float4 av = *(const float4*)(arow + k0 + skq);
        float4 bv = *(const float4*)(brow + k0 + skq);
        __syncthreads();
        As[skq + 0][srow] = av.x; As[skq + 1][srow] = av.y;
        As[skq + 2][srow] = av.z; As[skq + 3][srow] = av.w;
        Bs[skq + 0][srow] = bv.x; Bs[skq + 1][srow] = bv.y;
        Bs[skq + 2][srow] = bv.z; Bs[skq + 3][srow] = bv.w;
        __syncthreads();
        #pragma unroll
        for (int k = 0; k < 8; ++k) {
            float a[8], bb2[8];
            *(float4*)(a)       = *(const float4*)&As[k][ty * 8];
            *(float4*)(a + 4)   = *(const float4*)&As[k][ty * 8 + 4];
            *(float4*)(bb2)     = *(const float4*)&Bs[k][tx * 4];        // half-tile 0
            *(float4*)(bb2 + 4) = *(const float4*)&Bs[k][64 + tx * 4];  // half-tile 1
            #pragma unroll
            for (int i = 0; i < 8; ++i)
                #pragma unroll
                for (int j = 0; j < 8; ++j)
                    acc[i][j] = fmaf(a[i], bb2[j], acc[i][j]);
        }
    }

    float bs[8];
    #pragma unroll
    for (int j = 0; j < 4; ++j) bs[j] = bias1[nt + tx * 4 + j] + bias2[nt + tx * 4 + j];
    #pragma unroll
    for (int j = 4; j < 8; ++j) bs[j] = bias1[nt + 64 + tx * 4 + j - 4] + bias2[nt + 64 + tx * 4 + j - 4];
    #pragma unroll
    for (int i = 0; i < 8; ++i) {
        size_t row = (size_t)(mt + ty * 8 + i);      // local chunk row
        float* cp0 = C + row * GDIM + nt + tx * 4;
        float* cp1 = C + row * GDIM + nt + 64 + tx * 4;
        float4 v0 = make_float4(acc[i][0] + bs[0], acc[i][1] + bs[1],
                                acc[i][2] + bs[2], acc[i][3] + bs[3]);
        float4 v1 = make_float4(acc[i][4] + bs[4], acc[i][5] + bs[5],
                                acc[i][6] + bs[6], acc[i][7] + bs[7]);
        *(float4*)cp0 = v0;
        *(float4*)cp1 = v1;
    }
}

// ---------------------------------------------------------------------------
// LSTM recurrence, 64 blocks: blk = dir*32 + bb; 2 batch elements per block.
// W streamed from L2 (Wt layout, lane-contiguous). gx loads and h stores are
// NON-TEMPORAL so the 2 MB of Wt stays L2-resident (round-5's 4.8 GB HBM
// refetch was W thrashed by these streams).
// ---------------------------------------------------------------------------
template<bool TOXBUF>
__global__ __launch_bounds__(1024)
void lstm_rec(const float* __restrict__ gx_f, const float* __restrict__ gx_b,
              const float4* __restrict__ Wt_f, const float4* __restrict__ Wt_b,
              float* __restrict__ xout, float* __restrict__ hbuf,
              float* __restrict__ state,
              int t0f, int t0b, int C, int init)
{
    const int blk = blockIdx.x;     // 0..63
    const int dir = blk >> 5;       // 0 = fwd, 1 = bwd
    const int bb = blk & 31;
    const int b0 = bb * 2, b1 = b0 + 1;
    const float* gx = dir ? gx_b : gx_f;
    const float4* Wt = dir ? Wt_b : Wt_f;
    const int j = threadIdx.x;      // gate index 0..1023

    __shared__ __align__(16) float h_lds[2][HDIM];
    __shared__ __align__(16) float g_lds[2][GDIM];

    float* st0 = state + (((size_t)dir * BSZ + b0) * 2) * HDIM;  // [h|c][256]
    float* st1 = state + (((size_t)dir * BSZ + b1) * 2) * HDIM;

    float c0 = 0.0f, c1 = 0.0f;
    if (j < HDIM) {
        if (init) {
            h_lds[0][j] = 0.0f; h_lds[1][j] = 0.0f;
        } else {
            h_lds[0][j] = st0[j];        c0 = st0[HDIM + j];
            h_lds[1][j] = st1[j];        c1 = st1[HDIM + j];
        }
    }
    const float4* Wp = Wt + j;      // lane-contiguous base
    __syncthreads();

    for (int s = 0; s < C; ++s) {
        const int tloc = dir ? (C - 1 - s) : s;
        const int tglob = (dir ? t0b : t0f) + tloc;
        const float* gxp = gx + ((size_t)tloc * BSZ) * GDIM + j;
        float gxv0 = __builtin_nontemporal_load(gxp + (size_t)b0 * GDIM);
        float gxv1 = __builtin_nontemporal_load(gxp + (size_t)b1 * GDIM);
        float acc0 = 0.0f, acc1 = 0.0f;
        #pragma unroll
        for (int kq = 0; kq < HDIM / 4; ++kq) {
            float4 w  = Wp[(size_t)kq * GDIM];
            float4 ha = *(const float4*)&h_lds[0][kq * 4];
            float4 hb = *(const float4*)&h_lds[1][kq * 4];
            acc0 = fmaf(w.x, ha.x, acc0); acc0 = fmaf(w.y, ha.y, acc0);
            acc0 = fmaf(w.z, ha.z, acc0); acc0 = fmaf(w.w, ha.w, acc0);
            acc1 = fmaf(w.x, hb.x, acc1); acc1 = fmaf(w.y, hb.y, acc1);
            acc1 = fmaf(w.z, hb.z, acc1); acc1 = fmaf(w.w, hb.w, acc1);
        }
        g_lds[0][j] = acc0 + gxv0;
        g_lds[1][j] = acc1 + gxv1;
        __syncthreads();   // all h reads done, all gates staged
        if (j < HDIM) {
            float i0 = sigf(g_lds[0][j]);
            float f0 = sigf(g_lds[0][j + 256]);
            float t0_ = tanhf(g_lds[0][j + 512]);
            float o0 = sigf(g_lds[0][j + 768]);
            c0 = f0 * c0 + i0 * t0_;
            float h0 = o0 * tanhf(c0);
            float i1 = sigf(g_lds[1][j]);
            float f1 = sigf(g_lds[1][j + 256]);
            float t1 = tanhf(g_lds[1][j + 512]);
            float o1 = sigf(g_lds[1][j + 768]);
            c1 = f1 * c1 + i1 * t1;
            float h1 = o1 * tanhf(c1);
            h_lds[0][j] = h0;
            h_lds[1][j] = h1;
            if (TOXBUF) {
                size_t base = ((size_t)tglob * BSZ) * 512 + (size_t)dir * HDIM + j;
                __builtin_nontemporal_store(h0, &xout[base + (size_t)b0 * 512]);
                __builtin_nontemporal_store(h1, &xout[base + (size_t)b1 * 512]);
            } else {
                size_t base = (((size_t)dir * C + tloc) * BSZ) * HDIM + j;
                hbuf[base + (size_t)b0 * HDIM] = h0;
                hbuf[base + (size_t)b1 * HDIM] = h1;
            }
        }
        __syncthreads();   // h_lds ready for next step
    }
    if (j < HDIM) {        // persist carry for next chunk
        st0[j] = h_lds[0][j];  st0[HDIM + j] = c0;
        st1[j] = h_lds[1][j];  st1[HDIM + j] = c1;
    }
}

// ---------------------------------------------------------------------------
// Partial emissions from one chunk of layer-1 h (both dirs).
// ---------------------------------------------------------------------------
__global__ __launch_bounds__(256)
void emis_part(const float* __restrict__ hbuf, const float* __restrict__ Wo,
               float* __restrict__ em_f, float* __restrict__ em_b,
               int t0f, int t0b, int C)
{
    __shared__ float Ws[128][33];
    const int dir = blockIdx.y;
    const int tid = threadIdx.x;
    const int r = tid >> 5;          // 0..7
    const int kk = tid & 31;
    const int mloc = blockIdx.x * 8 + r;      // 0..C*64-1
    const float* hrow = hbuf + ((size_t)dir * C * BSZ + mloc) * HDIM;
    float* emo = dir ? em_b : em_f;
    const int t0 = dir ? t0b : t0f;
    float acc = 0.0f;
    for (int kc = 0; kc < HDIM; kc += 128) {
        __syncthreads();
        for (int i = tid; i < KTAG * 128; i += 256) {
            int wk = i >> 7;         // tag row 0..31
            int k = i & 127;
            Ws[k][wk] = Wo[(size_t)wk * 512 + dir * HDIM + kc + k];
        }
        __syncthreads();
        #pragma unroll 8
        for (int k4 = 0; k4 < 32; ++k4) {
            float4 xv = *(const float4*)(hrow + kc + k4 * 4);
            acc = fmaf(xv.x, Ws[k4 * 4 + 0][kk], acc);
            acc = fmaf(xv.y, Ws[k4 * 4 + 1][kk], acc);
            acc = fmaf(xv.z, Ws[k4 * 4 + 2][kk], acc);
            acc = fmaf(xv.w, Ws[k4 * 4 + 3][kk], acc);
        }
    }
    const int tloc = mloc >> 6;
    const int b = mloc & 63;
    emo[(((size_t)(t0 + tloc)) * BSZ + b) * KTAG + kk] = acc;
}

// ---------------------------------------------------------------------------
// Viterbi: one block (64 threads, 32 active) per batch element.
// ---------------------------------------------------------------------------
__global__ __launch_bounds__(64)
void viterbi(const float* __restrict__ em_f, const float* __restrict__ em_b,
             const float* __restrict__ bo,
             const float* __restrict__ st, const float* __restrict__ en,
             const float* __restrict__ tr,
             unsigned char* __restrict__ bp, int* __restrict__ out)
{
    const int b = blockIdx.x;
    const int lane = threadIdx.x;
    __shared__ float s_tr[KTAG][KTAG + 1];
    __shared__ float s_sc[KTAG];
    __shared__ float s_fin[KTAG];
    for (int i = lane; i < KTAG * KTAG; i += 64)
        s_tr[i >> 5][i & 31] = tr[i];
    if (lane < KTAG) {
        size_t e0 = (size_t)b * KTAG + lane;
        s_sc[lane] = st[lane] + em_f[e0] + em_b[e0] + bo[lane];
    }
    __syncthreads();
    for (int t = 1; t < TLEN; ++t) {
        float best = -3.0e38f;
        int arg = 0;
        if (lane < KTAG) {
            #pragma unroll
            for (int i = 0; i < KTAG; ++i) {
                float c = s_sc[i] + s_tr[i][lane];
                if (c > best) { best = c; arg = i; }
            }
        }
        __syncthreads();
        if (lane < KTAG) {
            size_t et = ((size_t)t * BSZ + b) * KTAG + lane;
            s_sc[lane] = best + em_f[et] + em_b[et] + bo[lane];
            bp[((size_t)(t - 1) * BSZ + b) * KTAG + lane] = (unsigned char)arg;
        }
        __syncthreads();
    }
    if (lane < KTAG) s_fin[lane] = s_sc[lane] + en[lane];
    __syncthreads();
    if (lane == 0) {
        int tag = 0;
        float bv = s_fin[0];
        for (int i = 1; i < KTAG; ++i)
            if (s_fin[i] > bv) { bv = s_fin[i]; tag = i; }
        out[(size_t)b * TLEN + (TLEN - 1)] = tag;
        for (int t = TLEN - 2; t >= 0; --t) {
            tag = bp[((size_t)t * BSZ + b) * KTAG + tag];
            out[(size_t)b * TLEN + t] = tag;
        }
    }
}

// ---------------------------------------------------------------------------
extern "C" void kernel_launch(void* const* d_in, const int* in_sizes, int n_in,
                              void* d_out, int out_size, void* d_ws, size_t ws_size,
                              hipStream_t stream)
{
    (void)in_sizes; (void)n_in; (void)out_size;
    const int*   inputs     = (const int*)d_in[0];
    const float* emb        = (const float*)d_in[1];
    const float* W_ih_l0_f  = (const float*)d_in[2];
    const float* W_hh_l0_f  = (const float*)d_in[3];
    const float* b_ih_l0_f  = (const float*)d_in[4];
    const float* b_hh_l0_f  = (const float*)d_in[5];
    const float* W_ih_l0_b  = (const float*)d_in[6];
    const float* W_hh_l0_b  = (const float*)d_in[7];
    const float* b_ih_l0_b  = (const float*)d_in[8];
    const float* b_hh_l0_b  = (const float*)d_in[9];
    const float* W_ih_l1_f  = (const float*)d_in[10];
    const float* W_hh_l1_f  = (const float*)d_in[11];
    const float* b_ih_l1_f  = (const float*)d_in[12];
    const float* b_hh_l1_f  = (const float*)d_in[13];
    const float* W_ih_l1_b  = (const float*)d_in[14];
    const float* W_hh_l1_b  = (const float*)d_in[15];
    const float* b_ih_l1_b  = (const float*)d_in[16];
    const float* b_hh_l1_b  = (const float*)d_in[17];
    const float* W_out      = (const float*)d_in[18];
    const float* b_out      = (const float*)d_in[19];
    const float* start_tr   = (const float*)d_in[20];
    const float* end_tr     = (const float*)d_in[21];
    const float* trans      = (const float*)d_in[22];

    // workspace: xbuf 64MB | gx_f C*256KB | gx_b C*256KB | hbuf C*128KB |
    //   em_f 4MB | em_b 4MB | bp 1MB | state 512KB | wt_f 1MB | wt_b 1MB
    const size_t XBUF = 67108864;
    const size_t TAIL = 4194304ull * 2 + 1048576 + 524288 + 2097152;
    int C = 16;
    for (int cand = TLEN; cand >= 16; cand >>= 1) {
        size_t need = XBUF + (size_t)cand * (524288 + 131072) + TAIL;
        if (need <= ws_size) { C = cand; break; }
    }
    char* ws = (char*)d_ws;
    float* xbuf = (float*)(ws);
    float* gx_f = (float*)(ws + XBUF);
    float* gx_b = (float*)(ws + XBUF + (size_t)C * 262144);
    float* hbuf = (float*)(ws + XBUF + (size_t)C * 524288);
    char*  tail = ws + XBUF + (size_t)C * (524288 + 131072);
    float* em_f = (float*)(tail);
    float* em_b = (float*)(tail + 4194304);
    unsigned char* bp = (unsigned char*)(tail + 2 * 4194304);
    float* state = (float*)(tail + 2 * 4194304 + 1048576);
    float4* wt_f = (float4*)(tail + 2 * 4194304 + 1048576 + 524288);
    float4* wt_b = (float4*)(tail + 2 * 4194304 + 1048576 + 524288 + 1048576);
    int* outi = (int*)d_out;

    const int nc = TLEN / C;
    dim3 gg(C / 2, 16);   // (C*64/128) m-tiles x 2048/128 n-tiles

    // ----- layer 0 -----
    transpose_w<<<256, 256, 0, stream>>>(W_hh_l0_f, wt_f);
    transpose_w<<<256, 256, 0, stream>>>(W_hh_l0_b, wt_b);
    for (int c = 0; c < nc; ++c) {
        int t0f = c * C;
        int t0b = TLEN - (c + 1) * C;
        gemm_dual<EDIM, true><<<gg, 256, 0, stream>>>(
            emb, inputs, W_ih_l0_f, W_ih_l0_b,
            b_ih_l0_f, b_hh_l0_f, b_ih_l0_b, b_hh_l0_b,
            gx_f, gx_b, t0f, t0b, 0, 0);
        lstm_rec<true><<<64, 1024, 0, stream>>>(
            gx_f, gx_b, wt_f, wt_b, xbuf, nullptr, state,
            t0f, t0b, C, c == 0 ? 1 : 0);
    }
    // ----- layer 1 ----- (xbuf READ-ONLY here; h -> hbuf -> em parts)
    transpose_w<<<256, 256, 0, stream>>>(W_hh_l1_f, wt_f);
    transpose_w<<<256, 256, 0, stream>>>(W_hh_l1_b, wt_b);
    for (int c = 0; c < nc; ++c) {
        int t0f = c * C;
        int t0b = TLEN - (c + 1) * C;
        gemm_dual<512, false><<<gg, 256, 0, stream>>>(
            xbuf, nullptr, W_ih_l1_f, W_ih_l1_b,
            b_ih_l1_f, b_hh_l1_f, b_ih_l1_b, b_hh_l1_b,
            gx_f, gx_b, t0f, t0b, t0f * BSZ, t0b * BSZ);
        lstm_rec<false><<<64, 1024, 0, stream>>>(
            gx_f, gx_b, wt_f, wt_b, nullptr, hbuf, state,
            t0f, t0b, C, c == 0 ? 1 : 0);
        dim3 ge(C * 8, 2);
        emis_part<<<ge, 256, 0, stream>>>(hbuf, W_out, em_f, em_b, t0f, t0b, C);
    }

    // viterbi decode -> int32 tags
    viterbi<<<64, 64, 0, stream>>>(em_f, em_b, b_out, start_tr, end_tr, trans,
                                   bp, outi);
}